// Round 6
// baseline (117.437 us; speedup 1.0000x reference)
//
#include <hip/hip_runtime.h>
#include <math.h>

#define BB 2
#define NAT 2048
#define NTOK 256
#define POISON 1.0e8f

struct WS {
  double red[BB][17];   // n, swm, Swm_x[3], Swm_xgt[3], M[9]
  // 9 contiguous accumulators zeroed by k_atom block 0:
  double mse_num;
  double bond_num[BB];
  double bond_den[BB];
  double cem[BB];
  double cm[BB];
  int ticket;
  int pad;
  float Rf[BB][9];
  float muf[BB][3];     // mean of x_gt
  float mugf[BB][3];    // mean of x
  float wA[BB*NAT];
  float nucA[BB*NAT];
  float ligA[BB*NAT];
  // px = {x,y,z, bitcast(tok | polbit<<8)}, pg = {gx,gy,gz, mask}; masked atoms' coords poisoned
  float4 px[BB*NAT];
  float4 pg[BB*NAT];
};

// ---------------- K1: per-atom tables + packing (one wave per atom) ----------------
__global__ __launch_bounds__(256) void k_atom(
    const float* __restrict__ x, const float* __restrict__ xgt,
    const float* __restrict__ mask, const float* __restrict__ A,
    const float* __restrict__ poly, const float* __restrict__ lig,
    const float* __restrict__ dna, const float* __restrict__ rna,
    WS* __restrict__ ws) {
  int tid = threadIdx.x;
  int gid = blockIdx.x * 4 + (tid >> 6);   // atom index
  int lane = tid & 63;
  int b = gid >> 11;
  float4 v = ((const float4*)(A + (size_t)gid * NTOK))[lane];
  float s = v.x * (float)(4*lane) + v.y * (float)(4*lane+1)
          + v.z * (float)(4*lane+2) + v.w * (float)(4*lane+3);
  for (int off = 32; off; off >>= 1) s += __shfl_xor(s, off);
  if (lane == 0) {
    int t = (int)(s + 0.5f);
    float d  = dna[b*NTOK + t], r = rna[b*NTOK + t];
    float li = lig[b*NTOK + t], po = poly[b*NTOK + t];
    float m  = mask[gid];
    bool ok = (m != 0.0f);
    ws->wA[gid]   = 1.0f + 5.0f*d + 5.0f*r + 10.0f*li;
    ws->nucA[gid] = d + r;
    ws->ligA[gid] = li;
    int meta = t | ((po != 0.0f && ok) ? 256 : 0);
    const float* xp = x   + (size_t)gid * 3;
    const float* gp = xgt + (size_t)gid * 3;
    ws->px[gid] = ok ? make_float4(xp[0], xp[1], xp[2], __int_as_float(meta))
                     : make_float4(POISON, POISON, POISON, __int_as_float(meta));
    ws->pg[gid] = ok ? make_float4(gp[0], gp[1], gp[2], m)
                     : make_float4(POISON, POISON, POISON, m);
  }
  if (blockIdx.x == 0) {  // zero pair accumulators + ticket (k_pair runs 2 kernels later)
    if (tid < 9) (&ws->mse_num)[tid] = 0.0;
    if (tid == 9) ws->ticket = 0;
  }
}

// ---------------- K2: moments (f64) + 3x3 SVD, one block per batch ----------------
__device__ void svd3(const double* red, float* Rf, float* muf, float* mugf) {
  double swm = red[1];
  double mug[3] = { red[2]/swm, red[3]/swm, red[4]/swm };  // mean x
  double mu[3]  = { red[5]/swm, red[6]/swm, red[7]/swm };  // mean x_gt
  double H[3][3];
  for (int i = 0; i < 3; i++)
    for (int j = 0; j < 3; j++)
      H[i][j] = red[8 + 3*i + j] - swm * mug[i] * mu[j];
  double Km[3][3];
  for (int i = 0; i < 3; i++)
    for (int j = 0; j < 3; j++)
      Km[i][j] = H[0][i]*H[0][j] + H[1][i]*H[1][j] + H[2][i]*H[2][j];
  double V[3][3] = {{1,0,0},{0,1,0},{0,0,1}};
  for (int sweep = 0; sweep < 15; sweep++) {
    double off2 = Km[0][1]*Km[0][1] + Km[0][2]*Km[0][2] + Km[1][2]*Km[1][2];
    double dia2 = Km[0][0]*Km[0][0] + Km[1][1]*Km[1][1] + Km[2][2]*Km[2][2];
    if (off2 < 1e-26 * dia2 + 1e-300) break;
    for (int p = 0; p < 2; p++) {
      for (int q = p + 1; q < 3; q++) {
        double apq = Km[p][q];
        if (fabs(apq) < 1e-300) continue;
        double theta = (Km[q][q] - Km[p][p]) / (2.0 * apq);
        double t = 1.0 / (fabs(theta) + sqrt(theta*theta + 1.0));
        if (theta < 0) t = -t;
        double c = 1.0 / sqrt(t*t + 1.0), sn = t * c;
        for (int k = 0; k < 3; k++) {
          double akp = Km[k][p], akq = Km[k][q];
          Km[k][p] = c*akp - sn*akq;
          Km[k][q] = sn*akp + c*akq;
        }
        for (int k = 0; k < 3; k++) {
          double apk = Km[p][k], aqk = Km[q][k];
          Km[p][k] = c*apk - sn*aqk;
          Km[q][k] = sn*apk + c*aqk;
        }
        for (int k = 0; k < 3; k++) {
          double vkp = V[k][p], vkq = V[k][q];
          V[k][p] = c*vkp - sn*vkq;
          V[k][q] = sn*vkp + c*vkq;
        }
      }
    }
  }
  double ev[3] = { Km[0][0], Km[1][1], Km[2][2] };
  int id[3] = {0, 1, 2};
  for (int i = 0; i < 2; i++)
    for (int j = i + 1; j < 3; j++)
      if (ev[id[j]] > ev[id[i]]) { int tmp = id[i]; id[i] = id[j]; id[j] = tmp; }
  double Uc[3][3], Vc[3][3], S[3];
  for (int k = 0; k < 3; k++) {
    int e = id[k];
    double v0 = V[0][e], v1 = V[1][e], v2 = V[2][e];
    Vc[k][0] = v0; Vc[k][1] = v1; Vc[k][2] = v2;
    double u0 = H[0][0]*v0 + H[0][1]*v1 + H[0][2]*v2;
    double u1 = H[1][0]*v0 + H[1][1]*v1 + H[1][2]*v2;
    double u2 = H[2][0]*v0 + H[2][1]*v1 + H[2][2]*v2;
    double nrm = sqrt(u0*u0 + u1*u1 + u2*u2);
    S[k] = nrm;
    if (nrm > 1e-12) { u0 /= nrm; u1 /= nrm; u2 /= nrm; }
    Uc[k][0] = u0; Uc[k][1] = u1; Uc[k][2] = u2;
  }
  if (S[2] <= 1e-12 * (S[0] > 0 ? S[0] : 1.0)) {
    Uc[2][0] = Uc[0][1]*Uc[1][2] - Uc[0][2]*Uc[1][1];
    Uc[2][1] = Uc[0][2]*Uc[1][0] - Uc[0][0]*Uc[1][2];
    Uc[2][2] = Uc[0][0]*Uc[1][1] - Uc[0][1]*Uc[1][0];
  }
  double detU = Uc[0][0]*(Uc[1][1]*Uc[2][2]-Uc[1][2]*Uc[2][1])
              - Uc[1][0]*(Uc[0][1]*Uc[2][2]-Uc[0][2]*Uc[2][1])
              + Uc[2][0]*(Uc[0][1]*Uc[1][2]-Uc[0][2]*Uc[1][1]);
  double detV = Vc[0][0]*(Vc[1][1]*Vc[2][2]-Vc[1][2]*Vc[2][1])
              - Vc[1][0]*(Vc[0][1]*Vc[2][2]-Vc[0][2]*Vc[2][1])
              + Vc[2][0]*(Vc[0][1]*Vc[1][2]-Vc[0][2]*Vc[1][1]);
  double dsign = (detU * detV < 0.0) ? -1.0 : 1.0;
  for (int i = 0; i < 3; i++)
    for (int j = 0; j < 3; j++)
      Rf[3*i+j] = (float)(Uc[0][i]*Vc[0][j] + Uc[1][i]*Vc[1][j] + dsign*Uc[2][i]*Vc[2][j]);
  for (int i = 0; i < 3; i++) {
    muf[i]  = (float)mu[i];
    mugf[i] = (float)mug[i];
  }
}

__global__ __launch_bounds__(256) void k_redsvd(WS* __restrict__ ws) {
  int b = blockIdx.x;
  int tid = threadIdx.x;
  int lane = tid & 63;
  int wv = tid >> 6;
  double acc[17];
  for (int k = 0; k < 17; k++) acc[k] = 0.0;
  for (int a = tid; a < NAT; a += 256) {
    int gid = b * NAT + a;
    float4 p = ws->px[gid];
    float4 g = ws->pg[gid];
    float m = g.w;
    if (m == 0.0f) continue;  // masked atoms (poisoned coords) skipped
    double wm = (double)(ws->wA[gid] * m);
    double x0 = p.x, x1 = p.y, x2 = p.z;
    double g0 = g.x, g1 = g.y, g2 = g.z;
    acc[0] += (double)m;
    acc[1] += wm;
    acc[2] += wm*x0; acc[3] += wm*x1; acc[4] += wm*x2;
    acc[5] += wm*g0; acc[6] += wm*g1; acc[7] += wm*g2;
    acc[8]  += wm*x0*g0; acc[9]  += wm*x0*g1; acc[10] += wm*x0*g2;
    acc[11] += wm*x1*g0; acc[12] += wm*x1*g1; acc[13] += wm*x1*g2;
    acc[14] += wm*x2*g0; acc[15] += wm*x2*g1; acc[16] += wm*x2*g2;
  }
  for (int k = 0; k < 17; k++)
    for (int off = 32; off; off >>= 1) acc[k] += __shfl_xor(acc[k], off);
  __shared__ double part[4][17];
  if (lane == 0)
    for (int k = 0; k < 17; k++) part[wv][k] = acc[k];
  __syncthreads();
  if (tid < 17)
    ws->red[b][tid] = part[0][tid] + part[1][tid] + part[2][tid] + part[3][tid];
  __syncthreads();
  if (tid == 0) svd3(ws->red[b], ws->Rf[b], ws->muf[b], ws->mugf[b]);
}

// ------ K3: pair sums (4 rows x 1024 cols per block) + fused MSE + last-block combine ------
__global__ __launch_bounds__(256) void k_pair(const float* __restrict__ tb,
                                              WS* __restrict__ ws,
                                              float* __restrict__ out) {
  int tid = threadIdx.x, lane = tid & 63, wv = tid >> 6;
  int half = blockIdx.x & 1;           // which 1024-column half
  int rowg = blockIdx.x >> 1;
  int gid = rowg * 4 + wv;             // row atom index (block never straddles batch)
  int b = gid >> 11;
  int a = gid & (NAT - 1);
  const float4* __restrict__ pxb = ws->px + (size_t)b * NAT;
  const float4* __restrict__ pgb = ws->pg + (size_t)b * NAT;
  float4 pa = pxb[a];
  float4 ga = pgb[a];
  float ma = ga.w;
  float nuca = ws->nucA[gid];
  float lm = ws->ligA[gid] * ma;       // row-constant bond gate
  bool dob = (lm != 0.0f);
  float thresh = (nuca > 0.5f) ? 30.0f : 15.0f;
  int ta = __float_as_int(pa.w) & 255;
  const float* __restrict__ tbrow = tb + ((size_t)b * NTOK + ta) * NTOK;

  const float K1 = 0.60653066f;   // e^-0.5
  const float K2 = 0.36787944f;   // e^-1
  const float K3 = 0.13533528f;   // e^-2
  const float K4 = 0.018315639f;  // e^-4

  float bnum = 0.f, bden = 0.f, cemv = 0.f, cmv = 0.f;
  int c0 = half * (NAT / 2);
  #pragma unroll 4
  for (int k = 0; k < (NAT / 2) / 64; k++) {
    int c = c0 + lane + 64 * k;
    float4 pc = pxb[c];
    float4 gc = pgb[c];
    float d0 = pa.x-pc.x, d1 = pa.y-pc.y, d2 = pa.z-pc.z;
    float dxv = sqrtf(d0*d0 + d1*d1 + d2*d2);
    float e0 = ga.x-gc.x, e1 = ga.y-gc.y, e2 = ga.z-gc.z;
    float dgv = sqrtf(e0*e0 + e1*e1 + e2*e2);
    float diff = dxv - dgv;
    if (dob) {
      int meta = __float_as_int(pc.w);
      float tbv = tbrow[meta & 255];
      float bm = (meta & 256) ? tbv : 0.0f;   // masked cols have polbit cleared
      bnum += diff * diff * bm;
      bden += bm;
    }
    float dd = fabsf(diff);
    float E = __expf(dd);
    float e = __builtin_amdgcn_rcpf(fmaf(E, K1, 1.0f))
            + __builtin_amdgcn_rcpf(fmaf(E, K2, 1.0f))
            + __builtin_amdgcn_rcpf(fmaf(E, K3, 1.0f))
            + __builtin_amdgcn_rcpf(fmaf(E, K4, 1.0f));
    float pml = (dgv < thresh) ? 1.0f : 0.0f;  // masked cols poisoned -> dgv huge -> 0
    cemv += e * pml;
    cmv  += pml;
  }
  // remove the diagonal (c==a) contribution: dd=0 -> e=3.2163288, pml=1
  if (half == (a >> 10) && lane == (a & 63)) {
    cemv -= 3.2163288f;
    cmv  -= 1.0f;
  }

  float msef = 0.0f;
  if (lane == 0 && half == 0 && ma != 0.0f) {
    const float* R = ws->Rf[b];
    const float* mu = ws->muf[b];
    const float* mug = ws->mugf[b];
    float c0f = ga.x - mu[0], c1f = ga.y - mu[1], c2f = ga.z - mu[2];
    float a0 = R[0]*c0f + R[1]*c1f + R[2]*c2f + mug[0];
    float a1 = R[3]*c0f + R[4]*c1f + R[5]*c2f + mug[1];
    float a2 = R[6]*c0f + R[7]*c1f + R[8]*c2f + mug[2];
    float q0 = pa.x - a0, q1 = pa.y - a1, q2 = pa.z - a2;
    msef = ws->wA[gid] * ma * (q0*q0 + q1*q1 + q2*q2);
  }

  float vals[5] = { lm * bnum, lm * bden, 0.25f * ma * cemv, ma * cmv, msef };
  for (int k = 0; k < 5; k++)
    for (int off = 32; off; off >>= 1) vals[k] += __shfl_xor(vals[k], off);
  __shared__ double part[4][5];
  if (lane == 0)
    for (int k = 0; k < 5; k++) part[wv][k] = (double)vals[k];
  __syncthreads();
  if (tid < 5) {
    int k = tid;
    double s = part[0][k] + part[1][k] + part[2][k] + part[3][k];
    double* dst = (k == 0) ? &ws->bond_num[b] : (k == 1) ? &ws->bond_den[b]
                : (k == 2) ? &ws->cem[b]      : (k == 3) ? &ws->cm[b]
                : &ws->mse_num;
    atomicAdd(dst, s);
  }
  __syncthreads();   // drains the atomics (waitcnt before barrier)

  // last block combines; all reads go through the coherent atomic path
  __shared__ int sticket;
  if (tid == 0) sticket = atomicAdd(&ws->ticket, 1);
  __syncthreads();
  if (sticket == (int)gridDim.x - 1 && tid == 0) {
    double mse_num = atomicAdd(&ws->mse_num, 0.0);
    const double wt = (4.0*4.0 + 16.0*16.0) / ((4.0+16.0)*(4.0+16.0));  // 0.68
    double lsum = 0.0;
    for (int bb = 0; bb < BB; bb++) {
      double lmse  = mse_num / (3.0 * ws->red[bb][0]);   // red written in prev kernel
      double lbond = atomicAdd(&ws->bond_num[bb], 0.0) / atomicAdd(&ws->bond_den[bb], 0.0);
      double lddt  = atomicAdd(&ws->cem[bb], 0.0) / atomicAdd(&ws->cm[bb], 0.0);
      lsum += wt * (lmse + lbond) + (1.0 - lddt);
    }
    out[0] = (float)(lsum / BB);
  }
}

extern "C" void kernel_launch(void* const* d_in, const int* in_sizes, int n_in,
                              void* d_out, int out_size, void* d_ws, size_t ws_size,
                              hipStream_t stream) {
  const float* x    = (const float*)d_in[0];
  const float* xgt  = (const float*)d_in[1];
  const float* mask = (const float*)d_in[2];
  const float* A    = (const float*)d_in[3];
  const float* tb   = (const float*)d_in[4];
  const float* poly = (const float*)d_in[5];
  const float* lig  = (const float*)d_in[6];
  const float* dna  = (const float*)d_in[7];
  const float* rna  = (const float*)d_in[8];
  WS* ws = (WS*)d_ws;
  float* out = (float*)d_out;

  k_atom<<<BB * NAT / 4, 256, 0, stream>>>(x, xgt, mask, A, poly, lig, dna, rna, ws);
  k_redsvd<<<BB, 256, 0, stream>>>(ws);
  k_pair<<<BB * (NAT / 4) * 2, 256, 0, stream>>>(tb, ws, out);
}

// Round 7
// 54.170 us; speedup vs baseline: 2.1679x; 2.1679x over previous
//
#include <hip/hip_runtime.h>
#include <math.h>

#define BB 2
#define NAT 2048
#define NTOK 256
#define POISON 1.0e8f
#define NPB 2048              // number of k_pair blocks (BB * NAT/4 * 2)

struct WS {
  double red[BB][17];         // n, swm, Swm_x[3], Swm_xgt[3], M[9]
  float Rf[BB][9];
  float muf[BB][3];           // mean of x_gt
  float mugf[BB][3];          // mean of x
  float wA[BB*NAT];
  float nucA[BB*NAT];
  float ligA[BB*NAT];
  // px = {x,y,z, bitcast(tok | polbit<<8)}, pg = {gx,gy,gz, mask}; masked atoms poisoned
  float4 px[BB*NAT];
  float4 pg[BB*NAT];
  // per-block partials: {bond_num, bond_den, cem, cm, mse} (+3 pad -> 64B slot)
  double partials[NPB][8];
};

// ---------------- K1: per-atom tables + packing (one wave per atom) ----------------
__global__ __launch_bounds__(256) void k_atom(
    const float* __restrict__ x, const float* __restrict__ xgt,
    const float* __restrict__ mask, const float* __restrict__ A,
    const float* __restrict__ poly, const float* __restrict__ lig,
    const float* __restrict__ dna, const float* __restrict__ rna,
    WS* __restrict__ ws) {
  int tid = threadIdx.x;
  int gid = blockIdx.x * 4 + (tid >> 6);   // atom index
  int lane = tid & 63;
  int b = gid >> 11;
  float4 v = ((const float4*)(A + (size_t)gid * NTOK))[lane];
  float s = v.x * (float)(4*lane) + v.y * (float)(4*lane+1)
          + v.z * (float)(4*lane+2) + v.w * (float)(4*lane+3);
  for (int off = 32; off; off >>= 1) s += __shfl_xor(s, off);
  if (lane == 0) {
    int t = (int)(s + 0.5f);
    float d  = dna[b*NTOK + t], r = rna[b*NTOK + t];
    float li = lig[b*NTOK + t], po = poly[b*NTOK + t];
    float m  = mask[gid];
    bool ok = (m != 0.0f);
    ws->wA[gid]   = 1.0f + 5.0f*d + 5.0f*r + 10.0f*li;
    ws->nucA[gid] = d + r;
    ws->ligA[gid] = li;
    int meta = t | ((po != 0.0f && ok) ? 256 : 0);
    const float* xp = x   + (size_t)gid * 3;
    const float* gp = xgt + (size_t)gid * 3;
    ws->px[gid] = ok ? make_float4(xp[0], xp[1], xp[2], __int_as_float(meta))
                     : make_float4(POISON, POISON, POISON, __int_as_float(meta));
    ws->pg[gid] = ok ? make_float4(gp[0], gp[1], gp[2], m)
                     : make_float4(POISON, POISON, POISON, m);
  }
}

// ---------------- K2: moments (f64) + 3x3 SVD, one block per batch ----------------
__device__ void svd3(const double* red, float* Rf, float* muf, float* mugf) {
  double swm = red[1];
  double mug[3] = { red[2]/swm, red[3]/swm, red[4]/swm };  // mean x
  double mu[3]  = { red[5]/swm, red[6]/swm, red[7]/swm };  // mean x_gt
  double H[3][3];
  for (int i = 0; i < 3; i++)
    for (int j = 0; j < 3; j++)
      H[i][j] = red[8 + 3*i + j] - swm * mug[i] * mu[j];
  double Km[3][3];
  for (int i = 0; i < 3; i++)
    for (int j = 0; j < 3; j++)
      Km[i][j] = H[0][i]*H[0][j] + H[1][i]*H[1][j] + H[2][i]*H[2][j];
  double V[3][3] = {{1,0,0},{0,1,0},{0,0,1}};
  for (int sweep = 0; sweep < 15; sweep++) {
    double off2 = Km[0][1]*Km[0][1] + Km[0][2]*Km[0][2] + Km[1][2]*Km[1][2];
    double dia2 = Km[0][0]*Km[0][0] + Km[1][1]*Km[1][1] + Km[2][2]*Km[2][2];
    if (off2 < 1e-26 * dia2 + 1e-300) break;
    for (int p = 0; p < 2; p++) {
      for (int q = p + 1; q < 3; q++) {
        double apq = Km[p][q];
        if (fabs(apq) < 1e-300) continue;
        double theta = (Km[q][q] - Km[p][p]) / (2.0 * apq);
        double t = 1.0 / (fabs(theta) + sqrt(theta*theta + 1.0));
        if (theta < 0) t = -t;
        double c = 1.0 / sqrt(t*t + 1.0), sn = t * c;
        for (int k = 0; k < 3; k++) {
          double akp = Km[k][p], akq = Km[k][q];
          Km[k][p] = c*akp - sn*akq;
          Km[k][q] = sn*akp + c*akq;
        }
        for (int k = 0; k < 3; k++) {
          double apk = Km[p][k], aqk = Km[q][k];
          Km[p][k] = c*apk - sn*aqk;
          Km[q][k] = sn*apk + c*aqk;
        }
        for (int k = 0; k < 3; k++) {
          double vkp = V[k][p], vkq = V[k][q];
          V[k][p] = c*vkp - sn*vkq;
          V[k][q] = sn*vkp + c*vkq;
        }
      }
    }
  }
  double ev[3] = { Km[0][0], Km[1][1], Km[2][2] };
  int id[3] = {0, 1, 2};
  for (int i = 0; i < 2; i++)
    for (int j = i + 1; j < 3; j++)
      if (ev[id[j]] > ev[id[i]]) { int tmp = id[i]; id[i] = id[j]; id[j] = tmp; }
  double Uc[3][3], Vc[3][3], S[3];
  for (int k = 0; k < 3; k++) {
    int e = id[k];
    double v0 = V[0][e], v1 = V[1][e], v2 = V[2][e];
    Vc[k][0] = v0; Vc[k][1] = v1; Vc[k][2] = v2;
    double u0 = H[0][0]*v0 + H[0][1]*v1 + H[0][2]*v2;
    double u1 = H[1][0]*v0 + H[1][1]*v1 + H[1][2]*v2;
    double u2 = H[2][0]*v0 + H[2][1]*v1 + H[2][2]*v2;
    double nrm = sqrt(u0*u0 + u1*u1 + u2*u2);
    S[k] = nrm;
    if (nrm > 1e-12) { u0 /= nrm; u1 /= nrm; u2 /= nrm; }
    Uc[k][0] = u0; Uc[k][1] = u1; Uc[k][2] = u2;
  }
  if (S[2] <= 1e-12 * (S[0] > 0 ? S[0] : 1.0)) {
    Uc[2][0] = Uc[0][1]*Uc[1][2] - Uc[0][2]*Uc[1][1];
    Uc[2][1] = Uc[0][2]*Uc[1][0] - Uc[0][0]*Uc[1][2];
    Uc[2][2] = Uc[0][0]*Uc[1][1] - Uc[0][1]*Uc[1][0];
  }
  double detU = Uc[0][0]*(Uc[1][1]*Uc[2][2]-Uc[1][2]*Uc[2][1])
              - Uc[1][0]*(Uc[0][1]*Uc[2][2]-Uc[0][2]*Uc[2][1])
              + Uc[2][0]*(Uc[0][1]*Uc[1][2]-Uc[0][2]*Uc[1][1]);
  double detV = Vc[0][0]*(Vc[1][1]*Vc[2][2]-Vc[1][2]*Vc[2][1])
              - Vc[1][0]*(Vc[0][1]*Vc[2][2]-Vc[0][2]*Vc[2][1])
              + Vc[2][0]*(Vc[0][1]*Vc[1][2]-Vc[0][2]*Vc[1][1]);
  double dsign = (detU * detV < 0.0) ? -1.0 : 1.0;
  for (int i = 0; i < 3; i++)
    for (int j = 0; j < 3; j++)
      Rf[3*i+j] = (float)(Uc[0][i]*Vc[0][j] + Uc[1][i]*Vc[1][j] + dsign*Uc[2][i]*Vc[2][j]);
  for (int i = 0; i < 3; i++) {
    muf[i]  = (float)mu[i];
    mugf[i] = (float)mug[i];
  }
}

__global__ __launch_bounds__(256) void k_redsvd(WS* __restrict__ ws) {
  int b = blockIdx.x;
  int tid = threadIdx.x;
  int lane = tid & 63;
  int wv = tid >> 6;
  double acc[17];
  for (int k = 0; k < 17; k++) acc[k] = 0.0;
  for (int a = tid; a < NAT; a += 256) {
    int gid = b * NAT + a;
    float4 p = ws->px[gid];
    float4 g = ws->pg[gid];
    float m = g.w;
    if (m == 0.0f) continue;  // masked atoms (poisoned coords) skipped
    double wm = (double)(ws->wA[gid] * m);
    double x0 = p.x, x1 = p.y, x2 = p.z;
    double g0 = g.x, g1 = g.y, g2 = g.z;
    acc[0] += (double)m;
    acc[1] += wm;
    acc[2] += wm*x0; acc[3] += wm*x1; acc[4] += wm*x2;
    acc[5] += wm*g0; acc[6] += wm*g1; acc[7] += wm*g2;
    acc[8]  += wm*x0*g0; acc[9]  += wm*x0*g1; acc[10] += wm*x0*g2;
    acc[11] += wm*x1*g0; acc[12] += wm*x1*g1; acc[13] += wm*x1*g2;
    acc[14] += wm*x2*g0; acc[15] += wm*x2*g1; acc[16] += wm*x2*g2;
  }
  for (int k = 0; k < 17; k++)
    for (int off = 32; off; off >>= 1) acc[k] += __shfl_xor(acc[k], off);
  __shared__ double part[4][17];
  if (lane == 0)
    for (int k = 0; k < 17; k++) part[wv][k] = acc[k];
  __syncthreads();
  if (tid < 17)
    ws->red[b][tid] = part[0][tid] + part[1][tid] + part[2][tid] + part[3][tid];
  __syncthreads();
  if (tid == 0) svd3(ws->red[b], ws->Rf[b], ws->muf[b], ws->mugf[b]);
}

// ------ K3: pair sums (4 rows x 1024 cols per block) + fused MSE; plain-store partials ------
__global__ __launch_bounds__(256) void k_pair(const float* __restrict__ tb,
                                              WS* __restrict__ ws) {
  int tid = threadIdx.x, lane = tid & 63, wv = tid >> 6;
  int half = blockIdx.x & 1;           // which 1024-column half
  int rowg = blockIdx.x >> 1;
  int gid = rowg * 4 + wv;             // row atom index (block never straddles batch)
  int b = gid >> 11;
  int a = gid & (NAT - 1);
  const float4* __restrict__ pxb = ws->px + (size_t)b * NAT;
  const float4* __restrict__ pgb = ws->pg + (size_t)b * NAT;
  float4 pa = pxb[a];
  float4 ga = pgb[a];
  float ma = ga.w;
  float nuca = ws->nucA[gid];
  float lm = ws->ligA[gid] * ma;       // row-constant bond gate
  bool dob = (lm != 0.0f);
  float thresh = (nuca > 0.5f) ? 30.0f : 15.0f;
  int ta = __float_as_int(pa.w) & 255;
  const float* __restrict__ tbrow = tb + ((size_t)b * NTOK + ta) * NTOK;

  const float K1 = 0.60653066f;   // e^-0.5
  const float K2 = 0.36787944f;   // e^-1
  const float K3 = 0.13533528f;   // e^-2
  const float K4 = 0.018315639f;  // e^-4

  float bnum = 0.f, bden = 0.f, cemv = 0.f, cmv = 0.f;
  int c0 = half * (NAT / 2);
  #pragma unroll 4
  for (int k = 0; k < (NAT / 2) / 64; k++) {
    int c = c0 + lane + 64 * k;
    float4 pc = pxb[c];
    float4 gc = pgb[c];
    float d0 = pa.x-pc.x, d1 = pa.y-pc.y, d2 = pa.z-pc.z;
    float dxv = sqrtf(d0*d0 + d1*d1 + d2*d2);
    float e0 = ga.x-gc.x, e1 = ga.y-gc.y, e2 = ga.z-gc.z;
    float dgv = sqrtf(e0*e0 + e1*e1 + e2*e2);
    float diff = dxv - dgv;
    if (dob) {
      int meta = __float_as_int(pc.w);
      float tbv = tbrow[meta & 255];
      float bm = (meta & 256) ? tbv : 0.0f;   // masked cols have polbit cleared
      bnum += diff * diff * bm;
      bden += bm;
    }
    float dd = fabsf(diff);
    float E = __expf(dd);
    float e = __builtin_amdgcn_rcpf(fmaf(E, K1, 1.0f))
            + __builtin_amdgcn_rcpf(fmaf(E, K2, 1.0f))
            + __builtin_amdgcn_rcpf(fmaf(E, K3, 1.0f))
            + __builtin_amdgcn_rcpf(fmaf(E, K4, 1.0f));
    float pml = (dgv < thresh) ? 1.0f : 0.0f;  // masked cols poisoned -> dgv huge -> 0
    cemv += e * pml;
    cmv  += pml;
  }
  // remove the diagonal (c==a) contribution: dd=0 -> e=3.2163288, pml=1
  if (half == (a >> 10) && lane == (a & 63)) {
    cemv -= 3.2163288f;
    cmv  -= 1.0f;
  }

  float msef = 0.0f;
  if (lane == 0 && half == 0 && ma != 0.0f) {
    const float* R = ws->Rf[b];
    const float* mu = ws->muf[b];
    const float* mug = ws->mugf[b];
    float c0f = ga.x - mu[0], c1f = ga.y - mu[1], c2f = ga.z - mu[2];
    float a0 = R[0]*c0f + R[1]*c1f + R[2]*c2f + mug[0];
    float a1 = R[3]*c0f + R[4]*c1f + R[5]*c2f + mug[1];
    float a2 = R[6]*c0f + R[7]*c1f + R[8]*c2f + mug[2];
    float q0 = pa.x - a0, q1 = pa.y - a1, q2 = pa.z - a2;
    msef = ws->wA[gid] * ma * (q0*q0 + q1*q1 + q2*q2);
  }

  float vals[5] = { lm * bnum, lm * bden, 0.25f * ma * cemv, ma * cmv, msef };
  for (int k = 0; k < 5; k++)
    for (int off = 32; off; off >>= 1) vals[k] += __shfl_xor(vals[k], off);
  __shared__ double part[4][5];
  if (lane == 0)
    for (int k = 0; k < 5; k++) part[wv][k] = (double)vals[k];
  __syncthreads();
  if (tid < 5)   // plain store to this block's private 64B slot — no atomics
    ws->partials[blockIdx.x][tid] = part[0][tid] + part[1][tid] + part[2][tid] + part[3][tid];
}

// ---------------- K4: reduce partials + combine (one block) ----------------
__global__ __launch_bounds__(256) void k_final(const WS* __restrict__ ws,
                                               float* __restrict__ out) {
  int tid = threadIdx.x, lane = tid & 63, wv = tid >> 6;
  // blocks [0, NPB/2) are batch 0, [NPB/2, NPB) are batch 1
  double acc[10];
  for (int k = 0; k < 10; k++) acc[k] = 0.0;
  for (int s = tid; s < NPB; s += 256) {
    int bb = (s >= NPB/2) ? 1 : 0;
    const double* p = ws->partials[s];
    acc[bb*5+0] += p[0]; acc[bb*5+1] += p[1]; acc[bb*5+2] += p[2];
    acc[bb*5+3] += p[3]; acc[bb*5+4] += p[4];
  }
  for (int k = 0; k < 10; k++)
    for (int off = 32; off; off >>= 1) acc[k] += __shfl_xor(acc[k], off);
  __shared__ double part[4][10];
  if (lane == 0)
    for (int k = 0; k < 10; k++) part[wv][k] = acc[k];
  __syncthreads();
  if (tid == 0) {
    double t10[10];
    for (int k = 0; k < 10; k++)
      t10[k] = part[0][k] + part[1][k] + part[2][k] + part[3][k];
    double mse_num = t10[4] + t10[9];   // mse slot summed over both batches
    const double wt = (4.0*4.0 + 16.0*16.0) / ((4.0+16.0)*(4.0+16.0));  // 0.68
    double lsum = 0.0;
    for (int bb = 0; bb < BB; bb++) {
      double lmse  = mse_num / (3.0 * ws->red[bb][0]);
      double lbond = t10[bb*5+0] / t10[bb*5+1];
      double lddt  = t10[bb*5+2] / t10[bb*5+3];
      lsum += wt * (lmse + lbond) + (1.0 - lddt);
    }
    out[0] = (float)(lsum / BB);
  }
}

extern "C" void kernel_launch(void* const* d_in, const int* in_sizes, int n_in,
                              void* d_out, int out_size, void* d_ws, size_t ws_size,
                              hipStream_t stream) {
  const float* x    = (const float*)d_in[0];
  const float* xgt  = (const float*)d_in[1];
  const float* mask = (const float*)d_in[2];
  const float* A    = (const float*)d_in[3];
  const float* tb   = (const float*)d_in[4];
  const float* poly = (const float*)d_in[5];
  const float* lig  = (const float*)d_in[6];
  const float* dna  = (const float*)d_in[7];
  const float* rna  = (const float*)d_in[8];
  WS* ws = (WS*)d_ws;
  float* out = (float*)d_out;

  k_atom<<<BB * NAT / 4, 256, 0, stream>>>(x, xgt, mask, A, poly, lig, dna, rna, ws);
  k_redsvd<<<BB, 256, 0, stream>>>(ws);
  k_pair<<<NPB, 256, 0, stream>>>(tb, ws);
  k_final<<<1, 256, 0, stream>>>(ws, out);
}

// Round 8
// 52.413 us; speedup vs baseline: 2.2406x; 1.0335x over previous
//
#include <hip/hip_runtime.h>
#include <math.h>

#define BB 2
#define NAT 2048
#define NTOK 256
#define POISON 1.0e8f
#define NPB 2048              // number of k_pair blocks (BB * NAT/4 * 2)

#if __has_builtin(__builtin_amdgcn_sqrtf)
#define FSQRT __builtin_amdgcn_sqrtf
#else
#define FSQRT sqrtf
#endif
#if __has_builtin(__builtin_amdgcn_exp2f)
#define FEXP2 __builtin_amdgcn_exp2f
#else
#define FEXP2 exp2f
#endif

struct WS {
  double red[BB][17];         // n, swm, Swm_x[3], Swm_xgt[3], M[9]
  float Rf[BB][9];
  float muf[BB][3];           // mean of x_gt
  float mugf[BB][3];          // mean of x
  float wA[BB*NAT];
  float nucA[BB*NAT];
  float ligA[BB*NAT];
  // px = {x,y,z, bitcast(tok | polbit<<8)}, pg = {gx,gy,gz, mask}; masked atoms poisoned
  float4 px[BB*NAT];
  float4 pg[BB*NAT];
  // per-block partials: {bond_num, bond_den, cem, cm, mse} (+3 pad -> 64B slot)
  double partials[NPB][8];
};

// ---------------- K1: per-atom tables + packing (one wave per atom) ----------------
__global__ __launch_bounds__(256) void k_atom(
    const float* __restrict__ x, const float* __restrict__ xgt,
    const float* __restrict__ mask, const float* __restrict__ A,
    const float* __restrict__ poly, const float* __restrict__ lig,
    const float* __restrict__ dna, const float* __restrict__ rna,
    WS* __restrict__ ws) {
  int tid = threadIdx.x;
  int gid = blockIdx.x * 4 + (tid >> 6);   // atom index
  int lane = tid & 63;
  int b = gid >> 11;
  float4 v = ((const float4*)(A + (size_t)gid * NTOK))[lane];
  float s = v.x * (float)(4*lane) + v.y * (float)(4*lane+1)
          + v.z * (float)(4*lane+2) + v.w * (float)(4*lane+3);
  for (int off = 32; off; off >>= 1) s += __shfl_xor(s, off);
  if (lane == 0) {
    int t = (int)(s + 0.5f);
    float d  = dna[b*NTOK + t], r = rna[b*NTOK + t];
    float li = lig[b*NTOK + t], po = poly[b*NTOK + t];
    float m  = mask[gid];
    bool ok = (m != 0.0f);
    ws->wA[gid]   = 1.0f + 5.0f*d + 5.0f*r + 10.0f*li;
    ws->nucA[gid] = d + r;
    ws->ligA[gid] = li;
    int meta = t | ((po != 0.0f && ok) ? 256 : 0);
    const float* xp = x   + (size_t)gid * 3;
    const float* gp = xgt + (size_t)gid * 3;
    ws->px[gid] = ok ? make_float4(xp[0], xp[1], xp[2], __int_as_float(meta))
                     : make_float4(POISON, POISON, POISON, __int_as_float(meta));
    ws->pg[gid] = ok ? make_float4(gp[0], gp[1], gp[2], m)
                     : make_float4(POISON, POISON, POISON, m);
  }
}

// ---------------- K2: moments (f64) + 3x3 SVD, one block per batch ----------------
__device__ void svd3(const double* red, float* Rf, float* muf, float* mugf) {
  double swm = red[1];
  double mug[3] = { red[2]/swm, red[3]/swm, red[4]/swm };  // mean x
  double mu[3]  = { red[5]/swm, red[6]/swm, red[7]/swm };  // mean x_gt
  double H[3][3];
  for (int i = 0; i < 3; i++)
    for (int j = 0; j < 3; j++)
      H[i][j] = red[8 + 3*i + j] - swm * mug[i] * mu[j];
  double Km[3][3];
  for (int i = 0; i < 3; i++)
    for (int j = 0; j < 3; j++)
      Km[i][j] = H[0][i]*H[0][j] + H[1][i]*H[1][j] + H[2][i]*H[2][j];
  double V[3][3] = {{1,0,0},{0,1,0},{0,0,1}};
  for (int sweep = 0; sweep < 15; sweep++) {
    double off2 = Km[0][1]*Km[0][1] + Km[0][2]*Km[0][2] + Km[1][2]*Km[1][2];
    double dia2 = Km[0][0]*Km[0][0] + Km[1][1]*Km[1][1] + Km[2][2]*Km[2][2];
    if (off2 < 1e-26 * dia2 + 1e-300) break;
    for (int p = 0; p < 2; p++) {
      for (int q = p + 1; q < 3; q++) {
        double apq = Km[p][q];
        if (fabs(apq) < 1e-300) continue;
        double theta = (Km[q][q] - Km[p][p]) / (2.0 * apq);
        double t = 1.0 / (fabs(theta) + sqrt(theta*theta + 1.0));
        if (theta < 0) t = -t;
        double c = 1.0 / sqrt(t*t + 1.0), sn = t * c;
        for (int k = 0; k < 3; k++) {
          double akp = Km[k][p], akq = Km[k][q];
          Km[k][p] = c*akp - sn*akq;
          Km[k][q] = sn*akp + c*akq;
        }
        for (int k = 0; k < 3; k++) {
          double apk = Km[p][k], aqk = Km[q][k];
          Km[p][k] = c*apk - sn*aqk;
          Km[q][k] = sn*apk + c*aqk;
        }
        for (int k = 0; k < 3; k++) {
          double vkp = V[k][p], vkq = V[k][q];
          V[k][p] = c*vkp - sn*vkq;
          V[k][q] = sn*vkp + c*vkq;
        }
      }
    }
  }
  double ev[3] = { Km[0][0], Km[1][1], Km[2][2] };
  int id[3] = {0, 1, 2};
  for (int i = 0; i < 2; i++)
    for (int j = i + 1; j < 3; j++)
      if (ev[id[j]] > ev[id[i]]) { int tmp = id[i]; id[i] = id[j]; id[j] = tmp; }
  double Uc[3][3], Vc[3][3], S[3];
  for (int k = 0; k < 3; k++) {
    int e = id[k];
    double v0 = V[0][e], v1 = V[1][e], v2 = V[2][e];
    Vc[k][0] = v0; Vc[k][1] = v1; Vc[k][2] = v2;
    double u0 = H[0][0]*v0 + H[0][1]*v1 + H[0][2]*v2;
    double u1 = H[1][0]*v0 + H[1][1]*v1 + H[1][2]*v2;
    double u2 = H[2][0]*v0 + H[2][1]*v1 + H[2][2]*v2;
    double nrm = sqrt(u0*u0 + u1*u1 + u2*u2);
    S[k] = nrm;
    if (nrm > 1e-12) { u0 /= nrm; u1 /= nrm; u2 /= nrm; }
    Uc[k][0] = u0; Uc[k][1] = u1; Uc[k][2] = u2;
  }
  if (S[2] <= 1e-12 * (S[0] > 0 ? S[0] : 1.0)) {
    Uc[2][0] = Uc[0][1]*Uc[1][2] - Uc[0][2]*Uc[1][1];
    Uc[2][1] = Uc[0][2]*Uc[1][0] - Uc[0][0]*Uc[1][2];
    Uc[2][2] = Uc[0][0]*Uc[1][1] - Uc[0][1]*Uc[1][0];
  }
  double detU = Uc[0][0]*(Uc[1][1]*Uc[2][2]-Uc[1][2]*Uc[2][1])
              - Uc[1][0]*(Uc[0][1]*Uc[2][2]-Uc[0][2]*Uc[2][1])
              + Uc[2][0]*(Uc[0][1]*Uc[1][2]-Uc[0][2]*Uc[1][1]);
  double detV = Vc[0][0]*(Vc[1][1]*Vc[2][2]-Vc[1][2]*Vc[2][1])
              - Vc[1][0]*(Vc[0][1]*Vc[2][2]-Vc[0][2]*Vc[2][1])
              + Vc[2][0]*(Vc[0][1]*Vc[1][2]-Vc[0][2]*Vc[1][1]);
  double dsign = (detU * detV < 0.0) ? -1.0 : 1.0;
  for (int i = 0; i < 3; i++)
    for (int j = 0; j < 3; j++)
      Rf[3*i+j] = (float)(Uc[0][i]*Vc[0][j] + Uc[1][i]*Vc[1][j] + dsign*Uc[2][i]*Vc[2][j]);
  for (int i = 0; i < 3; i++) {
    muf[i]  = (float)mu[i];
    mugf[i] = (float)mug[i];
  }
}

__global__ __launch_bounds__(256) void k_redsvd(WS* __restrict__ ws) {
  int b = blockIdx.x;
  int tid = threadIdx.x;
  int lane = tid & 63;
  int wv = tid >> 6;
  double acc[17];
  for (int k = 0; k < 17; k++) acc[k] = 0.0;
  for (int a = tid; a < NAT; a += 256) {
    int gid = b * NAT + a;
    float4 p = ws->px[gid];
    float4 g = ws->pg[gid];
    float m = g.w;
    if (m == 0.0f) continue;  // masked atoms (poisoned coords) skipped
    double wm = (double)(ws->wA[gid] * m);
    double x0 = p.x, x1 = p.y, x2 = p.z;
    double g0 = g.x, g1 = g.y, g2 = g.z;
    acc[0] += (double)m;
    acc[1] += wm;
    acc[2] += wm*x0; acc[3] += wm*x1; acc[4] += wm*x2;
    acc[5] += wm*g0; acc[6] += wm*g1; acc[7] += wm*g2;
    acc[8]  += wm*x0*g0; acc[9]  += wm*x0*g1; acc[10] += wm*x0*g2;
    acc[11] += wm*x1*g0; acc[12] += wm*x1*g1; acc[13] += wm*x1*g2;
    acc[14] += wm*x2*g0; acc[15] += wm*x2*g1; acc[16] += wm*x2*g2;
  }
  for (int k = 0; k < 17; k++)
    for (int off = 32; off; off >>= 1) acc[k] += __shfl_xor(acc[k], off);
  __shared__ double part[4][17];
  if (lane == 0)
    for (int k = 0; k < 17; k++) part[wv][k] = acc[k];
  __syncthreads();
  if (tid < 17)
    ws->red[b][tid] = part[0][tid] + part[1][tid] + part[2][tid] + part[3][tid];
  __syncthreads();
  if (tid == 0) svd3(ws->red[b], ws->Rf[b], ws->muf[b], ws->mugf[b]);
}

// ------ K3: pair sums, LDS-staged column tiles, 4 rows x 1024 cols per block ------
__global__ __launch_bounds__(256) void k_pair(const float* __restrict__ tb,
                                              WS* __restrict__ ws) {
  int tid = threadIdx.x, lane = tid & 63, wv = tid >> 6;
  int half = blockIdx.x & 1;           // which 1024-column half
  int rowg = blockIdx.x >> 1;
  int gid = rowg * 4 + wv;             // row atom index (block never straddles batch)
  int b = gid >> 11;
  int a = gid & (NAT - 1);
  const float4* __restrict__ pxb = ws->px + (size_t)b * NAT;
  const float4* __restrict__ pgb = ws->pg + (size_t)b * NAT;
  float4 pa = pxb[a];
  float4 ga = pgb[a];
  float ma = ga.w;
  float nuca = ws->nucA[gid];
  float lm = ws->ligA[gid] * ma;       // row-constant bond gate
  bool dob = (lm != 0.0f);
  float thresh = (nuca > 0.5f) ? 30.0f : 15.0f;
  int ta = __float_as_int(pa.w) & 255;
  const float* __restrict__ tbrow = tb + ((size_t)b * NTOK + ta) * NTOK;

  const float K1 = 0.60653066f;   // e^-0.5
  const float K2 = 0.36787944f;   // e^-1
  const float K3 = 0.13533528f;   // e^-2
  const float K4 = 0.018315639f;  // e^-4
  const float LOG2E = 1.4426950408889634f;

  __shared__ float4 spx[256];
  __shared__ float4 spg[256];

  float bnum = 0.f, bden = 0.f, cemv = 0.f, cmv = 0.f;
  int base = half * (NAT / 2);
  for (int t = 0; t < 4; t++) {        // 4 tiles of 256 columns
    int cb = base + t * 256;
    __syncthreads();
    spx[tid] = pxb[cb + tid];
    spg[tid] = pgb[cb + tid];
    __syncthreads();
    #pragma unroll
    for (int k = 0; k < 4; k++) {
      int cl = lane + 64 * k;
      float4 pc = spx[cl];
      float4 gc = spg[cl];
      float d0 = pa.x-pc.x, d1 = pa.y-pc.y, d2 = pa.z-pc.z;
      float dxv = FSQRT(d0*d0 + d1*d1 + d2*d2);
      float e0 = ga.x-gc.x, e1 = ga.y-gc.y, e2 = ga.z-gc.z;
      float dgv = FSQRT(e0*e0 + e1*e1 + e2*e2);
      float diff = dxv - dgv;
      if (dob) {
        int meta = __float_as_int(pc.w);
        float tbv = tbrow[meta & 255];
        float bm = (meta & 256) ? tbv : 0.0f;   // masked cols have polbit cleared
        bnum += diff * diff * bm;
        bden += bm;
      }
      float dd = fabsf(diff);
      float E = FEXP2(dd * LOG2E);
      float e = __builtin_amdgcn_rcpf(fmaf(E, K1, 1.0f))
              + __builtin_amdgcn_rcpf(fmaf(E, K2, 1.0f))
              + __builtin_amdgcn_rcpf(fmaf(E, K3, 1.0f))
              + __builtin_amdgcn_rcpf(fmaf(E, K4, 1.0f));
      float pml = (dgv < thresh) ? 1.0f : 0.0f;  // masked cols poisoned -> dgv huge -> 0
      cemv += e * pml;
      cmv  += pml;
    }
  }
  // remove the diagonal (c==a) contribution: dd=0 -> e=3.2163288, pml=1
  if (half == (a >> 10) && lane == (a & 63)) {
    cemv -= 3.2163288f;
    cmv  -= 1.0f;
  }

  float msef = 0.0f;
  if (lane == 0 && half == 0 && ma != 0.0f) {
    const float* R = ws->Rf[b];
    const float* mu = ws->muf[b];
    const float* mug = ws->mugf[b];
    float c0f = ga.x - mu[0], c1f = ga.y - mu[1], c2f = ga.z - mu[2];
    float a0 = R[0]*c0f + R[1]*c1f + R[2]*c2f + mug[0];
    float a1 = R[3]*c0f + R[4]*c1f + R[5]*c2f + mug[1];
    float a2 = R[6]*c0f + R[7]*c1f + R[8]*c2f + mug[2];
    float q0 = pa.x - a0, q1 = pa.y - a1, q2 = pa.z - a2;
    msef = ws->wA[gid] * ma * (q0*q0 + q1*q1 + q2*q2);
  }

  float vals[5] = { lm * bnum, lm * bden, 0.25f * ma * cemv, ma * cmv, msef };
  for (int k = 0; k < 5; k++)
    for (int off = 32; off; off >>= 1) vals[k] += __shfl_xor(vals[k], off);
  __shared__ double part[4][5];
  if (lane == 0)
    for (int k = 0; k < 5; k++) part[wv][k] = (double)vals[k];
  __syncthreads();
  if (tid < 5)   // plain store to this block's private 64B slot — no atomics
    ws->partials[blockIdx.x][tid] = part[0][tid] + part[1][tid] + part[2][tid] + part[3][tid];
}

// ---------------- K4: reduce partials + combine (one block) ----------------
__global__ __launch_bounds__(256) void k_final(const WS* __restrict__ ws,
                                               float* __restrict__ out) {
  int tid = threadIdx.x, lane = tid & 63, wv = tid >> 6;
  // blocks [0, NPB/2) are batch 0, [NPB/2, NPB) are batch 1
  double acc[10];
  for (int k = 0; k < 10; k++) acc[k] = 0.0;
  for (int s = tid; s < NPB; s += 256) {
    int bb = (s >= NPB/2) ? 1 : 0;
    const double* p = ws->partials[s];
    acc[bb*5+0] += p[0]; acc[bb*5+1] += p[1]; acc[bb*5+2] += p[2];
    acc[bb*5+3] += p[3]; acc[bb*5+4] += p[4];
  }
  for (int k = 0; k < 10; k++)
    for (int off = 32; off; off >>= 1) acc[k] += __shfl_xor(acc[k], off);
  __shared__ double part[4][10];
  if (lane == 0)
    for (int k = 0; k < 10; k++) part[wv][k] = acc[k];
  __syncthreads();
  if (tid == 0) {
    double t10[10];
    for (int k = 0; k < 10; k++)
      t10[k] = part[0][k] + part[1][k] + part[2][k] + part[3][k];
    double mse_num = t10[4] + t10[9];   // mse slot summed over both batches
    const double wt = (4.0*4.0 + 16.0*16.0) / ((4.0+16.0)*(4.0+16.0));  // 0.68
    double lsum = 0.0;
    for (int bb = 0; bb < BB; bb++) {
      double lmse  = mse_num / (3.0 * ws->red[bb][0]);
      double lbond = t10[bb*5+0] / t10[bb*5+1];
      double lddt  = t10[bb*5+2] / t10[bb*5+3];
      lsum += wt * (lmse + lbond) + (1.0 - lddt);
    }
    out[0] = (float)(lsum / BB);
  }
}

extern "C" void kernel_launch(void* const* d_in, const int* in_sizes, int n_in,
                              void* d_out, int out_size, void* d_ws, size_t ws_size,
                              hipStream_t stream) {
  const float* x    = (const float*)d_in[0];
  const float* xgt  = (const float*)d_in[1];
  const float* mask = (const float*)d_in[2];
  const float* A    = (const float*)d_in[3];
  const float* tb   = (const float*)d_in[4];
  const float* poly = (const float*)d_in[5];
  const float* lig  = (const float*)d_in[6];
  const float* dna  = (const float*)d_in[7];
  const float* rna  = (const float*)d_in[8];
  WS* ws = (WS*)d_ws;
  float* out = (float*)d_out;

  k_atom<<<BB * NAT / 4, 256, 0, stream>>>(x, xgt, mask, A, poly, lig, dna, rna, ws);
  k_redsvd<<<BB, 256, 0, stream>>>(ws);
  k_pair<<<NPB, 256, 0, stream>>>(tb, ws);
  k_final<<<1, 256, 0, stream>>>(ws, out);
}

// Round 9
// 48.501 us; speedup vs baseline: 2.4213x; 1.0807x over previous
//
#include <hip/hip_runtime.h>
#include <math.h>

#define BB 2
#define NAT 2048
#define NTOK 256
#define POISON 1.0e8f
#define NPB 2048              // k_pair blocks: (4096 rows / 8 per block) * 4 quarters

#if __has_builtin(__builtin_amdgcn_sqrtf)
#define FSQRT __builtin_amdgcn_sqrtf
#else
#define FSQRT sqrtf
#endif
#if __has_builtin(__builtin_amdgcn_exp2f)
#define FEXP2 __builtin_amdgcn_exp2f
#else
#define FEXP2 exp2f
#endif

struct WS {
  double red[BB][17];         // n, swm, Swm_x[3], Swm_xgt[3], M[9]
  float Rf[BB][9];
  float muf[BB][3];           // mean of x_gt
  float mugf[BB][3];          // mean of x
  float wA[BB*NAT];
  float nucA[BB*NAT];
  float ligA[BB*NAT];
  // px = {x,y,z, bitcast(tok | polbit<<8)}, pg = {gx,gy,gz, mask}; masked atoms poisoned
  float4 px[BB*NAT];
  float4 pg[BB*NAT];
  // SoA partials: {bond_num, bond_den, cem, cm, mse}[NPB] each
  double partials5[5 * NPB];
};

// ---------------- K1: per-atom tables + packing (one wave per atom) ----------------
__global__ __launch_bounds__(256) void k_atom(
    const float* __restrict__ x, const float* __restrict__ xgt,
    const float* __restrict__ mask, const float* __restrict__ A,
    const float* __restrict__ poly, const float* __restrict__ lig,
    const float* __restrict__ dna, const float* __restrict__ rna,
    WS* __restrict__ ws) {
  int tid = threadIdx.x;
  int gid = blockIdx.x * 4 + (tid >> 6);   // atom index
  int lane = tid & 63;
  int b = gid >> 11;
  float4 v = ((const float4*)(A + (size_t)gid * NTOK))[lane];
  float s = v.x * (float)(4*lane) + v.y * (float)(4*lane+1)
          + v.z * (float)(4*lane+2) + v.w * (float)(4*lane+3);
  for (int off = 32; off; off >>= 1) s += __shfl_xor(s, off);
  if (lane == 0) {
    int t = (int)(s + 0.5f);
    float d  = dna[b*NTOK + t], r = rna[b*NTOK + t];
    float li = lig[b*NTOK + t], po = poly[b*NTOK + t];
    float m  = mask[gid];
    bool ok = (m != 0.0f);
    ws->wA[gid]   = 1.0f + 5.0f*d + 5.0f*r + 10.0f*li;
    ws->nucA[gid] = d + r;
    ws->ligA[gid] = li;
    int meta = t | ((po != 0.0f && ok) ? 256 : 0);
    const float* xp = x   + (size_t)gid * 3;
    const float* gp = xgt + (size_t)gid * 3;
    ws->px[gid] = ok ? make_float4(xp[0], xp[1], xp[2], __int_as_float(meta))
                     : make_float4(POISON, POISON, POISON, __int_as_float(meta));
    ws->pg[gid] = ok ? make_float4(gp[0], gp[1], gp[2], m)
                     : make_float4(POISON, POISON, POISON, m);
  }
}

// ---------------- K2: moments (f64) + 3x3 SVD, one block per batch ----------------
__device__ void svd3(const double* red, float* Rf, float* muf, float* mugf) {
  double swm = red[1];
  double mug[3] = { red[2]/swm, red[3]/swm, red[4]/swm };  // mean x
  double mu[3]  = { red[5]/swm, red[6]/swm, red[7]/swm };  // mean x_gt
  double H[3][3];
  for (int i = 0; i < 3; i++)
    for (int j = 0; j < 3; j++)
      H[i][j] = red[8 + 3*i + j] - swm * mug[i] * mu[j];
  double Km[3][3];
  for (int i = 0; i < 3; i++)
    for (int j = 0; j < 3; j++)
      Km[i][j] = H[0][i]*H[0][j] + H[1][i]*H[1][j] + H[2][i]*H[2][j];
  double V[3][3] = {{1,0,0},{0,1,0},{0,0,1}};
  for (int sweep = 0; sweep < 8; sweep++) {
    double off2 = Km[0][1]*Km[0][1] + Km[0][2]*Km[0][2] + Km[1][2]*Km[1][2];
    double dia2 = Km[0][0]*Km[0][0] + Km[1][1]*Km[1][1] + Km[2][2]*Km[2][2];
    if (off2 < 1e-26 * dia2 + 1e-300) break;
    for (int p = 0; p < 2; p++) {
      for (int q = p + 1; q < 3; q++) {
        double apq = Km[p][q];
        if (fabs(apq) < 1e-300) continue;
        double theta = (Km[q][q] - Km[p][p]) / (2.0 * apq);
        double t = 1.0 / (fabs(theta) + sqrt(theta*theta + 1.0));
        if (theta < 0) t = -t;
        double c = 1.0 / sqrt(t*t + 1.0), sn = t * c;
        for (int k = 0; k < 3; k++) {
          double akp = Km[k][p], akq = Km[k][q];
          Km[k][p] = c*akp - sn*akq;
          Km[k][q] = sn*akp + c*akq;
        }
        for (int k = 0; k < 3; k++) {
          double apk = Km[p][k], aqk = Km[q][k];
          Km[p][k] = c*apk - sn*aqk;
          Km[q][k] = sn*apk + c*aqk;
        }
        for (int k = 0; k < 3; k++) {
          double vkp = V[k][p], vkq = V[k][q];
          V[k][p] = c*vkp - sn*vkq;
          V[k][q] = sn*vkp + c*vkq;
        }
      }
    }
  }
  double ev[3] = { Km[0][0], Km[1][1], Km[2][2] };
  int id[3] = {0, 1, 2};
  for (int i = 0; i < 2; i++)
    for (int j = i + 1; j < 3; j++)
      if (ev[id[j]] > ev[id[i]]) { int tmp = id[i]; id[i] = id[j]; id[j] = tmp; }
  double Uc[3][3], Vc[3][3], S[3];
  for (int k = 0; k < 3; k++) {
    int e = id[k];
    double v0 = V[0][e], v1 = V[1][e], v2 = V[2][e];
    Vc[k][0] = v0; Vc[k][1] = v1; Vc[k][2] = v2;
    double u0 = H[0][0]*v0 + H[0][1]*v1 + H[0][2]*v2;
    double u1 = H[1][0]*v0 + H[1][1]*v1 + H[1][2]*v2;
    double u2 = H[2][0]*v0 + H[2][1]*v1 + H[2][2]*v2;
    double nrm = sqrt(u0*u0 + u1*u1 + u2*u2);
    S[k] = nrm;
    if (nrm > 1e-12) { u0 /= nrm; u1 /= nrm; u2 /= nrm; }
    Uc[k][0] = u0; Uc[k][1] = u1; Uc[k][2] = u2;
  }
  if (S[2] <= 1e-12 * (S[0] > 0 ? S[0] : 1.0)) {
    Uc[2][0] = Uc[0][1]*Uc[1][2] - Uc[0][2]*Uc[1][1];
    Uc[2][1] = Uc[0][2]*Uc[1][0] - Uc[0][0]*Uc[1][2];
    Uc[2][2] = Uc[0][0]*Uc[1][1] - Uc[0][1]*Uc[1][0];
  }
  double detU = Uc[0][0]*(Uc[1][1]*Uc[2][2]-Uc[1][2]*Uc[2][1])
              - Uc[1][0]*(Uc[0][1]*Uc[2][2]-Uc[0][2]*Uc[2][1])
              + Uc[2][0]*(Uc[0][1]*Uc[1][2]-Uc[0][2]*Uc[1][1]);
  double detV = Vc[0][0]*(Vc[1][1]*Vc[2][2]-Vc[1][2]*Vc[2][1])
              - Vc[1][0]*(Vc[0][1]*Vc[2][2]-Vc[0][2]*Vc[2][1])
              + Vc[2][0]*(Vc[0][1]*Vc[1][2]-Vc[0][2]*Vc[1][1]);
  double dsign = (detU * detV < 0.0) ? -1.0 : 1.0;
  for (int i = 0; i < 3; i++)
    for (int j = 0; j < 3; j++)
      Rf[3*i+j] = (float)(Uc[0][i]*Vc[0][j] + Uc[1][i]*Vc[1][j] + dsign*Uc[2][i]*Vc[2][j]);
  for (int i = 0; i < 3; i++) {
    muf[i]  = (float)mu[i];
    mugf[i] = (float)mug[i];
  }
}

__global__ __launch_bounds__(256) void k_redsvd(WS* __restrict__ ws) {
  int b = blockIdx.x;
  int tid = threadIdx.x;
  int lane = tid & 63;
  int wv = tid >> 6;
  double acc[17];
  for (int k = 0; k < 17; k++) acc[k] = 0.0;
  for (int a = tid; a < NAT; a += 256) {
    int gid = b * NAT + a;
    float4 p = ws->px[gid];
    float4 g = ws->pg[gid];
    float m = g.w;
    if (m == 0.0f) continue;  // masked atoms (poisoned coords) skipped
    double wm = (double)(ws->wA[gid] * m);
    double x0 = p.x, x1 = p.y, x2 = p.z;
    double g0 = g.x, g1 = g.y, g2 = g.z;
    acc[0] += (double)m;
    acc[1] += wm;
    acc[2] += wm*x0; acc[3] += wm*x1; acc[4] += wm*x2;
    acc[5] += wm*g0; acc[6] += wm*g1; acc[7] += wm*g2;
    acc[8]  += wm*x0*g0; acc[9]  += wm*x0*g1; acc[10] += wm*x0*g2;
    acc[11] += wm*x1*g0; acc[12] += wm*x1*g1; acc[13] += wm*x1*g2;
    acc[14] += wm*x2*g0; acc[15] += wm*x2*g1; acc[16] += wm*x2*g2;
  }
  for (int k = 0; k < 17; k++)
    for (int off = 32; off; off >>= 1) acc[k] += __shfl_xor(acc[k], off);
  __shared__ double part[4][17];
  if (lane == 0)
    for (int k = 0; k < 17; k++) part[wv][k] = acc[k];
  __syncthreads();
  if (tid < 17)
    ws->red[b][tid] = part[0][tid] + part[1][tid] + part[2][tid] + part[3][tid];
  __syncthreads();
  if (tid == 0) svd3(ws->red[b], ws->Rf[b], ws->muf[b], ws->mugf[b]);
}

// ------ K3: pair sums. 2 rows/wave, 512-col quarter, LUT sigmoid-sum, SoA partials ------
__global__ __launch_bounds__(256) void k_pair(const float* __restrict__ tb,
                                              WS* __restrict__ ws) {
  int tid = threadIdx.x, lane = tid & 63, wv = tid >> 6;
  int quarter = blockIdx.x & 3;        // which 512-column quarter
  int rowblk = blockIdx.x >> 2;        // 8 consecutive rows per block
  int gid0 = rowblk * 8 + wv * 2;      // first of this wave's two rows
  int gid1 = gid0 + 1;
  int b = gid0 >> 11;                  // 8 | 2048: block never straddles batch
  int a0 = gid0 & (NAT - 1), a1 = gid1 & (NAT - 1);

  // ---- build sigmoid-sum LUT: lut[j] = {E(j/16), E((j+1)/16) - E(j/16)}, j=0..255 ----
  __shared__ float2 lut[256];
  {
    const float K1 = 0.60653066f, K2 = 0.36787944f, K3 = 0.13533528f, K4 = 0.018315639f;
    const float LOG2E = 1.4426950408889634f;
    float dd0 = (float)tid * 0.0625f;
    float Ea = FEXP2(dd0 * LOG2E);
    float Eb = FEXP2((dd0 + 0.0625f) * LOG2E);
    float e0 = __builtin_amdgcn_rcpf(fmaf(Ea, K1, 1.0f)) + __builtin_amdgcn_rcpf(fmaf(Ea, K2, 1.0f))
             + __builtin_amdgcn_rcpf(fmaf(Ea, K3, 1.0f)) + __builtin_amdgcn_rcpf(fmaf(Ea, K4, 1.0f));
    float e1 = __builtin_amdgcn_rcpf(fmaf(Eb, K1, 1.0f)) + __builtin_amdgcn_rcpf(fmaf(Eb, K2, 1.0f))
             + __builtin_amdgcn_rcpf(fmaf(Eb, K3, 1.0f)) + __builtin_amdgcn_rcpf(fmaf(Eb, K4, 1.0f));
    lut[tid] = make_float2(e0, e1 - e0);
  }
  __syncthreads();

  const float4* __restrict__ pxb = ws->px + (size_t)b * NAT;
  const float4* __restrict__ pgb = ws->pg + (size_t)b * NAT;
  float4 pa0 = pxb[a0], pa1 = pxb[a1];
  float4 ga0 = pgb[a0], ga1 = pgb[a1];
  float ma0 = ga0.w, ma1 = ga1.w;
  float lm0 = ws->ligA[gid0] * ma0, lm1 = ws->ligA[gid1] * ma1;
  bool dob = (lm0 != 0.0f) || (lm1 != 0.0f);
  float th0 = (ws->nucA[gid0] > 0.5f) ? 30.0f : 15.0f;
  float th1 = (ws->nucA[gid1] > 0.5f) ? 30.0f : 15.0f;
  const float* __restrict__ tbrow0 = tb + ((size_t)b * NTOK + (__float_as_int(pa0.w) & 255)) * NTOK;
  const float* __restrict__ tbrow1 = tb + ((size_t)b * NTOK + (__float_as_int(pa1.w) & 255)) * NTOK;

  float bnum0 = 0.f, bden0 = 0.f, cem0 = 0.f, cm0 = 0.f;
  float bnum1 = 0.f, bden1 = 0.f, cem1 = 0.f, cm1 = 0.f;
  int base = quarter * (NAT / 4);
  #pragma unroll 4
  for (int k = 0; k < (NAT / 4) / 64; k++) {   // 8 iterations
    int c = base + 64 * k + lane;
    float4 pc = pxb[c];
    float4 gc = pgb[c];
    // row 0
    float d0 = pa0.x-pc.x, d1 = pa0.y-pc.y, d2 = pa0.z-pc.z;
    float dxv0 = FSQRT(d0*d0 + d1*d1 + d2*d2);
    float e0 = ga0.x-gc.x, e1 = ga0.y-gc.y, e2 = ga0.z-gc.z;
    float dgv0 = FSQRT(e0*e0 + e1*e1 + e2*e2);
    float diff0 = dxv0 - dgv0;
    // row 1
    float f0 = pa1.x-pc.x, f1 = pa1.y-pc.y, f2 = pa1.z-pc.z;
    float dxv1 = FSQRT(f0*f0 + f1*f1 + f2*f2);
    float h0 = ga1.x-gc.x, h1 = ga1.y-gc.y, h2 = ga1.z-gc.z;
    float dgv1 = FSQRT(h0*h0 + h1*h1 + h2*h2);
    float diff1 = dxv1 - dgv1;
    if (dob) {
      int meta = __float_as_int(pc.w);
      float pol = (meta & 256) ? 1.0f : 0.0f;   // masked cols have polbit cleared
      float tv0 = tbrow0[meta & 255] * pol;
      float tv1 = tbrow1[meta & 255] * pol;
      bnum0 += diff0 * diff0 * tv0;  bden0 += tv0;
      bnum1 += diff1 * diff1 * tv1;  bden1 += tv1;
    }
    float t0 = fminf(fabsf(diff0) * 16.0f, 255.0f);
    float t1 = fminf(fabsf(diff1) * 16.0f, 255.0f);
    int i0 = (int)t0, i1 = (int)t1;
    float2 l0 = lut[i0], l1 = lut[i1];
    float ev0 = fmaf(t0 - (float)i0, l0.y, l0.x);
    float ev1 = fmaf(t1 - (float)i1, l1.y, l1.x);
    float pml0 = (dgv0 < th0) ? 1.0f : 0.0f;  // masked cols poisoned -> dgv huge -> 0
    float pml1 = (dgv1 < th1) ? 1.0f : 0.0f;
    cem0 += ev0 * pml0;  cm0 += pml0;
    cem1 += ev1 * pml1;  cm1 += pml1;
  }
  // remove diagonal (c==a) contribution: dd=0 -> E=3.2163288, pml=1
  if ((a0 >> 9) == quarter && lane == (a0 & 63)) { cem0 -= 3.2163288f; cm0 -= 1.0f; }
  if ((a1 >> 9) == quarter && lane == (a1 & 63)) { cem1 -= 3.2163288f; cm1 -= 1.0f; }

  float msef = 0.0f;
  if (lane == 0 && quarter == 0) {
    const float* R = ws->Rf[b];
    const float* mu = ws->muf[b];
    const float* mug = ws->mugf[b];
    if (ma0 != 0.0f) {
      float c0f = ga0.x - mu[0], c1f = ga0.y - mu[1], c2f = ga0.z - mu[2];
      float q0 = pa0.x - (R[0]*c0f + R[1]*c1f + R[2]*c2f + mug[0]);
      float q1 = pa0.y - (R[3]*c0f + R[4]*c1f + R[5]*c2f + mug[1]);
      float q2 = pa0.z - (R[6]*c0f + R[7]*c1f + R[8]*c2f + mug[2]);
      msef += ws->wA[gid0] * ma0 * (q0*q0 + q1*q1 + q2*q2);
    }
    if (ma1 != 0.0f) {
      float c0f = ga1.x - mu[0], c1f = ga1.y - mu[1], c2f = ga1.z - mu[2];
      float q0 = pa1.x - (R[0]*c0f + R[1]*c1f + R[2]*c2f + mug[0]);
      float q1 = pa1.y - (R[3]*c0f + R[4]*c1f + R[5]*c2f + mug[1]);
      float q2 = pa1.z - (R[6]*c0f + R[7]*c1f + R[8]*c2f + mug[2]);
      msef += ws->wA[gid1] * ma1 * (q0*q0 + q1*q1 + q2*q2);
    }
  }

  float vals[5] = { lm0*bnum0 + lm1*bnum1, lm0*bden0 + lm1*bden1,
                    0.25f*(ma0*cem0 + ma1*cem1), ma0*cm0 + ma1*cm1, msef };
  for (int k = 0; k < 5; k++)
    for (int off = 32; off; off >>= 1) vals[k] += __shfl_xor(vals[k], off);
  __shared__ double part[4][5];
  if (lane == 0)
    for (int k = 0; k < 5; k++) part[wv][k] = (double)vals[k];
  __syncthreads();
  if (tid < 5)   // plain store, SoA layout, no atomics
    ws->partials5[tid * NPB + blockIdx.x] =
        part[0][tid] + part[1][tid] + part[2][tid] + part[3][tid];
}

// ---------------- K4: reduce partials + combine (one block) ----------------
__global__ __launch_bounds__(256) void k_final(const WS* __restrict__ ws,
                                               float* __restrict__ out) {
  int tid = threadIdx.x, lane = tid & 63, wv = tid >> 6;
  // blocks [0, NPB/2) are batch 0 (rowblk*8 < 2048), rest batch 1
  double acc[10];
  for (int k = 0; k < 10; k++) acc[k] = 0.0;
  for (int s = tid; s < NPB; s += 256) {
    int bb = (s >= NPB/2) ? 1 : 0;
    #pragma unroll
    for (int k = 0; k < 5; k++)
      acc[bb*5+k] += ws->partials5[k * NPB + s];
  }
  for (int k = 0; k < 10; k++)
    for (int off = 32; off; off >>= 1) acc[k] += __shfl_xor(acc[k], off);
  __shared__ double part[4][10];
  if (lane == 0)
    for (int k = 0; k < 10; k++) part[wv][k] = acc[k];
  __syncthreads();
  if (tid == 0) {
    double t10[10];
    for (int k = 0; k < 10; k++)
      t10[k] = part[0][k] + part[1][k] + part[2][k] + part[3][k];
    double mse_num = t10[4] + t10[9];   // mse summed over both batches
    const double wt = (4.0*4.0 + 16.0*16.0) / ((4.0+16.0)*(4.0+16.0));  // 0.68
    double lsum = 0.0;
    for (int bb = 0; bb < BB; bb++) {
      double lmse  = mse_num / (3.0 * ws->red[bb][0]);
      double lbond = t10[bb*5+0] / t10[bb*5+1];
      double lddt  = t10[bb*5+2] / t10[bb*5+3];
      lsum += wt * (lmse + lbond) + (1.0 - lddt);
    }
    out[0] = (float)(lsum / BB);
  }
}

extern "C" void kernel_launch(void* const* d_in, const int* in_sizes, int n_in,
                              void* d_out, int out_size, void* d_ws, size_t ws_size,
                              hipStream_t stream) {
  const float* x    = (const float*)d_in[0];
  const float* xgt  = (const float*)d_in[1];
  const float* mask = (const float*)d_in[2];
  const float* A    = (const float*)d_in[3];
  const float* tb   = (const float*)d_in[4];
  const float* poly = (const float*)d_in[5];
  const float* lig  = (const float*)d_in[6];
  const float* dna  = (const float*)d_in[7];
  const float* rna  = (const float*)d_in[8];
  WS* ws = (WS*)d_ws;
  float* out = (float*)d_out;

  k_atom<<<BB * NAT / 4, 256, 0, stream>>>(x, xgt, mask, A, poly, lig, dna, rna, ws);
  k_redsvd<<<BB, 256, 0, stream>>>(ws);
  k_pair<<<NPB, 256, 0, stream>>>(tb, ws);
  k_final<<<1, 256, 0, stream>>>(ws, out);
}